// Round 7
// baseline (533.989 us; speedup 1.0000x reference)
//
#include <hip/hip_runtime.h>
#include <math.h>

// ---------------------------------------------------------------------------
// NatureCNN: conv×3 (implicit-im2col bf16 MFMA GEMMs, NHWC intermediates)
// | lin1+relu -> lin2 (bf16 MFMA) -> concat feat -> wih0 pre-act GEMMs (fp32)
// -> 2×(2-layer LSTM, MFMA gate-GEMM, 2 blocks × 16 segments) -> head.
// Round 7: fix LDS h-row stride 224B -> 256B (swizzle ^((row&7)<<4) spans
// 256B; 224B stride let writes/reads cross row boundaries -> corruption).
// ---------------------------------------------------------------------------

typedef __attribute__((ext_vector_type(4))) float f32x4;
typedef __attribute__((ext_vector_type(8))) short s16x8;
typedef __attribute__((ext_vector_type(8))) unsigned short u16x8;

__device__ __forceinline__ unsigned short f2bf(float f){
  union { float f; unsigned int u; } v; v.f = f;
  unsigned int r = (v.u + 0x7fffu + ((v.u >> 16) & 1u)) >> 16;
  return (unsigned short)r;
}

// ---------------------------------------------------------------------------
// prep kernels (tiny, memory-bound)
// ---------------------------------------------------------------------------
__global__ void cast_pad_k(const float* __restrict__ src, unsigned short* __restrict__ dst,
                           int rows, int ks, int kd){
  int total = rows*kd;
  for (int e = blockIdx.x*blockDim.x + threadIdx.x; e < total; e += gridDim.x*blockDim.x){
    int r = e / kd, k = e - r*kd;
    dst[e] = (k < ks) ? f2bf(src[(size_t)r*ks + k]) : (unsigned short)0;
  }
}
// OIHW -> O,(tap,ci)
__global__ void reorder_w_k(const float* __restrict__ src, unsigned short* __restrict__ dst,
                            int ocn, int cin, int khkw){
  int K = cin*khkw, total = ocn*K;
  for (int e = blockIdx.x*blockDim.x + threadIdx.x; e < total; e += gridDim.x*blockDim.x){
    int oc = e / K, r = e - oc*K;
    int tap = r / cin, ic = r - tap*cin;
    dst[e] = f2bf(src[(size_t)oc*K + ic*khkw + tap]);
  }
}
// wih0 [400][1536]: permute k<1024 from (oc*16+p) order to NHWC-flat (p*64+oc)
__global__ void permute_wih_k(const float* __restrict__ src, unsigned short* __restrict__ dst){
  int total = 400*1536;
  for (int e = blockIdx.x*blockDim.x + threadIdx.x; e < total; e += gridDim.x*blockDim.x){
    int g = e / 1536, k = e - g*1536;
    int ksrc = (k < 1024) ? ((k & 63)*16 + (k >> 6)) : k;
    dst[e] = f2bf(src[(size_t)g*1536 + ksrc]);
  }
}
// six [400][100] recurrent/l1 mats -> MFMA B-fragment order:
// dst[m][((tile*4+ks)*64+lane)*8+j] = bf16(W[tile*16+(lane&15)][ks*32+(lane>>4)*8+j])
// zero-padded for k>=100.  Each matrix: 25 tiles * 4 ks * 64 lanes * 8 = 51200.
__global__ void wfrag_k(const float* s0,const float* s1,const float* s2,
                        const float* s3,const float* s4,const float* s5,
                        unsigned short* __restrict__ dst){
  const float* srcs[6] = {s0,s1,s2,s3,s4,s5};
  const float* src = srcs[blockIdx.y];
  unsigned short* d = dst + (size_t)blockIdx.y*51200;
  for (int e = blockIdx.x*blockDim.x + threadIdx.x; e < 51200; e += gridDim.x*blockDim.x){
    int tile = e >> 11;
    int r = e & 2047;
    int ks = r >> 9;
    int l = (r >> 3) & 63;
    int j = e & 7;
    int gate = tile*16 + (l & 15);
    int k = ks*32 + ((l >> 4) << 3) + j;
    d[e] = (k < 100) ? f2bf(src[gate*100 + k]) : (unsigned short)0;
  }
}

// ---------------------------------------------------------------------------
// bf16 MFMA GEMM (unchanged, passing since round 2)
// ---------------------------------------------------------------------------
template<int BM,int BN,int WAVES_M,int WAVES_N,int AMODE,int CMODE,int RELU,int NGUARD,
         int CIN,int HI,int WI,int KH,int KW,int ST,int HO,int WO>
__global__ __launch_bounds__(256) void mgemm(
    const void* __restrict__ Av, const unsigned short* __restrict__ B,
    void* __restrict__ Cv, const float* __restrict__ bias,
    int M, int N, int K, int lda, int ldc, int cstride)
{
  constexpr int BK = 64;
  constexpr int WROWS = BM / WAVES_M;
  constexpr int WCOLS = BN / WAVES_N;
  constexpr int MF = WROWS / 16;
  constexpr int NF = WCOLS / 16;
  constexpr int HOWO = HO*WO;
  __shared__ unsigned short As[BM*BK];
  __shared__ unsigned short Bs[BN*BK];
  const int tid = threadIdx.x;
  const int bm = blockIdx.x * BM;
  const int bn = blockIdx.y * BN;
  const int lane = tid & 63, w = tid >> 6;
  const int wm = w / WAVES_N, wn = w % WAVES_N;
  const int m0 = wm * WROWS, n0 = wn * WCOLS;

  f32x4 acc[MF][NF] = {};

  const int ar = tid >> 1;
  const int as0 = 4 * (tid & 1);
  const int row_g = bm + ar;
  int a_n = 0, a_oy = 0, a_ox = 0;
  if (AMODE != 0){ a_n = row_g / HOWO; int p = row_g - a_n*HOWO; a_oy = p / WO; a_ox = p - a_oy*WO; }

  for (int kt = 0; kt < K; kt += BK){
    #pragma unroll
    for (int si = 0; si < 4; ++si){
      int s = as0 + si;
      int k0 = kt + s*8;
      u16x8 val;
      if constexpr (AMODE == 0){
        val = *(const u16x8*)((const unsigned short*)Av + (size_t)row_g*lda + k0);
      } else if constexpr (AMODE == 1){
        int ic = k0 >> 6, r = k0 & 63, ky = r >> 3;
        const float* src = (const float*)Av +
            (((size_t)(a_n*CIN + ic)*HI + a_oy*ST + ky)*WI + a_ox*ST);
        f32x4 f0 = *(const f32x4*)src;
        f32x4 f1 = *(const f32x4*)(src + 4);
        val[0]=f2bf(f0[0]); val[1]=f2bf(f0[1]); val[2]=f2bf(f0[2]); val[3]=f2bf(f0[3]);
        val[4]=f2bf(f1[0]); val[5]=f2bf(f1[1]); val[6]=f2bf(f1[2]); val[7]=f2bf(f1[3]);
      } else {
        int tap = k0 / CIN, ic0 = k0 - tap*CIN;
        int ky = tap / KW, kx = tap - ky*KW;
        const unsigned short* src = (const unsigned short*)Av +
            (((size_t)(a_n*HI + a_oy*ST + ky)*WI + a_ox*ST + kx)*CIN + ic0);
        val = *(const u16x8*)src;
      }
      int phys = s ^ ((ar >> 1) & 7);
      *(u16x8*)&As[ar*BK + phys*8] = val;
    }
    if constexpr (BN == 64){
      int br = tid >> 2, bs0 = 2*(tid & 3);
      #pragma unroll
      for (int si = 0; si < 2; ++si){
        int s = bs0 + si, k0 = kt + s*8;
        int n_g = bn + br;
        u16x8 val = {};
        if (!NGUARD || n_g < N) val = *(const u16x8*)(B + (size_t)n_g*K + k0);
        int phys = s ^ ((br >> 1) & 7);
        *(u16x8*)&Bs[br*BK + phys*8] = val;
      }
    } else {
      int br = tid >> 3, s = tid & 7, k0 = kt + s*8;
      int n_g = bn + br;
      u16x8 val = {};
      if (!NGUARD || n_g < N) val = *(const u16x8*)(B + (size_t)n_g*K + k0);
      int phys = s ^ ((br >> 1) & 7);
      *(u16x8*)&Bs[br*BK + phys*8] = val;
    }
    __syncthreads();
    #pragma unroll
    for (int ks = 0; ks < 2; ++ks){
      s16x8 a[MF], b[NF];
      #pragma unroll
      for (int i = 0; i < MF; ++i){
        int row = m0 + i*16 + (lane & 15);
        int phys = (ks*4 + (lane >> 4)) ^ ((row >> 1) & 7);
        a[i] = *(const s16x8*)&As[row*BK + phys*8];
      }
      #pragma unroll
      for (int j = 0; j < NF; ++j){
        int row = n0 + j*16 + (lane & 15);
        int phys = (ks*4 + (lane >> 4)) ^ ((row >> 1) & 7);
        b[j] = *(const s16x8*)&Bs[row*BK + phys*8];
      }
      #pragma unroll
      for (int i = 0; i < MF; ++i)
        #pragma unroll
        for (int j = 0; j < NF; ++j)
          acc[i][j] = __builtin_amdgcn_mfma_f32_16x16x32_bf16(a[i], b[j], acc[i][j], 0, 0, 0);
    }
    __syncthreads();
  }

  if constexpr (CMODE == 3){
    float* Cf = (float*)Cv;
    #pragma unroll
    for (int i = 0; i < MF; ++i)
      #pragma unroll
      for (int j = 0; j < NF; ++j){
        int col = bn + n0 + j*16 + (lane & 15);
        float bv = (bias && (!NGUARD || col < N)) ? bias[col] : 0.f;
        #pragma unroll
        for (int q = 0; q < 4; ++q){
          int row = bm + m0 + i*16 + (lane >> 4)*4 + q;
          float v = acc[i][j][q] + bv;
          if (RELU) v = fmaxf(v, 0.f);
          if (!NGUARD || col < N) Cf[(size_t)row*ldc + col] = v;
        }
      }
  } else {
    unsigned short* tile = As;
    #pragma unroll
    for (int i = 0; i < MF; ++i)
      #pragma unroll
      for (int j = 0; j < NF; ++j){
        int col = n0 + j*16 + (lane & 15);
        float bv = bias ? bias[bn + col] : 0.f;
        #pragma unroll
        for (int q = 0; q < 4; ++q){
          int row = m0 + i*16 + (lane >> 4)*4 + q;
          float v = acc[i][j][q] + bv;
          if (RELU) v = fmaxf(v, 0.f);
          tile[row*BN + col] = f2bf(v);
        }
      }
    __syncthreads();
    unsigned short* Cu = (unsigned short*)Cv;
    constexpr int CHUNKS = (BM*BN)/(256*8);
    #pragma unroll
    for (int c = 0; c < CHUNKS; ++c){
      int flat = tid*8 + c*2048;
      int row = flat / BN, col = flat - (flat/BN)*BN;
      u16x8 v = *(const u16x8*)&tile[flat];
      int rg = bm + row;
      size_t addr;
      if constexpr (CMODE == 0) addr = (size_t)rg*ldc + bn + col;
      else { int n = rg >> 4, p = rg & 15; addr = (size_t)n*cstride + p*64 + col; }
      *(u16x8*)&Cu[addr] = v;
    }
  }
}

// ---------------------------------------------------------------------------
// MFMA LSTM. 2 blocks x 16 segments, 512 threads (8 waves).
// Per step: gates[16][400] = h[16][100] @ W^T via 25 N-tiles (16x16x32),
// W held in registers as pre-packed B-fragments (constant across the phase).
// h: bf16 in LDS, ROW STRIDE 128 u16 (256 B), byte-swizzle ^((row&7)<<4)
// (swizzle is a bijection within each 256B row; k=100..127 pad stays zero).
// L1 x-part: 8-step mini-batches through the same MFMA path -> Xl1 (global,
// same-thread readback; drained by the vmcnt(0) each __syncthreads emits).
// Wave w owns N-tiles {w, w+8, w+16} (+24 for w==0).
// ---------------------------------------------------------------------------
__global__ __launch_bounds__(512,2) void lstm_k(
    const float* __restrict__ X0s, const float* __restrict__ X0r,
    const unsigned short* __restrict__ wfrag,   // 6 matrices x 51200
    const float* __restrict__ s_bih0, const float* __restrict__ s_bhh0,
    const float* __restrict__ s_bih1, const float* __restrict__ s_bhh1,
    const float* __restrict__ r_bih0, const float* __restrict__ r_bhh0,
    const float* __restrict__ r_bih1, const float* __restrict__ r_bhh1,
    float* __restrict__ Xl1ws, float* __restrict__ outS, float* __restrict__ outR)
{
  __shared__ alignas(16) unsigned short hbuf[18432];   // 9 slots x 16 rows x 128
  __shared__ alignas(16) unsigned short h1buf[4096];   // 2 slots x 16 rows x 128
  __shared__ float gates[6464];                        // [16][404] activated
  __shared__ float cbuf[3328];                         // [2][16][104]

  const int tid = threadIdx.x;
  const int lane = tid & 63, w = tid >> 6;
  const int colg = lane & 15;     // A-row / gate-col within tile
  const int krow = lane >> 4;     // 0..3
  const int b0 = blockIdx.x * 16;

  int TN[4];
  TN[0] = w; TN[1] = w + 8; TN[2] = w + 16; TN[3] = (w == 0) ? 24 : 0;

  s16x8 bfr[4][4];
  f32x4 acc[4];
  float xp[4][4];

  // zero-init LDS (k-pad of h rows must be 0; pads are never overwritten)
  for (int e = tid; e < 9216; e += 512) ((unsigned int*)hbuf)[e] = 0u;
  for (int e = tid; e < 2048; e += 512) ((unsigned int*)h1buf)[e] = 0u;
  for (int e = tid; e < 6464; e += 512) gates[e] = 0.f;
  for (int e = tid; e < 3328; e += 512) cbuf[e] = 0.f;
  __syncthreads();

  auto load_frags = [&](int mat){
    const unsigned short* base = wfrag + (size_t)mat*51200;
    #pragma unroll
    for (int i = 0; i < 4; ++i){
      #pragma unroll
      for (int ks = 0; ks < 4; ++ks)
        bfr[i][ks] = *(const s16x8*)(base + (((size_t)TN[i]*4 + ks)*64 + lane)*8);
    }
  };

  auto mm = [&](const unsigned short* hb, int rowbase){
    int row = rowbase + colg;
    const char* rp = (const char*)hb + row*256;
    int sw = (row & 7) << 4;
    s16x8 a[4];
    #pragma unroll
    for (int ks = 0; ks < 4; ++ks)
      a[ks] = *(const s16x8*)(rp + ((ks*64 + krow*16) ^ sw));
    #pragma unroll
    for (int i = 0; i < 4; ++i)
      #pragma unroll
      for (int q = 0; q < 4; ++q) acc[i][q] = 0.f;
    #pragma unroll
    for (int ks = 0; ks < 4; ++ks)
      #pragma unroll
      for (int i = 0; i < 4; ++i)
        acc[i] = __builtin_amdgcn_mfma_f32_16x16x32_bf16(a[ks], bfr[i][ks], acc[i], 0, 0, 0);
  };

  auto act_store = [&](const float* biasr){
    #pragma unroll
    for (int i = 0; i < 4; ++i){
      if (i == 3 && w != 0) continue;
      int gate = TN[i]*16 + colg;
      bool isG = (gate >= 200) && (gate < 300);
      float bsel = biasr[i];
      #pragma unroll
      for (int q = 0; q < 4; ++q){
        float pre = acc[i][q] + xp[i][q] + bsel;
        float xx = isG ? pre + pre : pre;
        float e = __expf(-xx);
        float sg = 1.0f / (1.0f + e);
        float v = isG ? (sg + sg - 1.0f) : sg;
        gates[(krow*4 + q)*404 + gate] = v;
      }
    }
  };

  auto update = [&](float* cb, unsigned short* hdst, int dstbase, float* gout){
    #pragma unroll
    for (int p = 0; p < 4; ++p){
      int slot = p*512 + tid;
      int seg = slot >> 7, j = slot & 127;
      if (j < 100){
        float* grow = gates + seg*404;
        float iv = grow[j], fv = grow[100+j], gv = grow[200+j], ov = grow[300+j];
        float cn = fv*cb[seg*104 + j] + iv*gv;
        cb[seg*104 + j] = cn;
        float e = __expf(-2.0f*fabsf(cn));
        float th = copysignf((1.0f - e)/(1.0f + e), cn);
        float hn = ov*th;
        int row = dstbase + seg;
        *(unsigned short*)((char*)hdst + row*256 + ((j*2) ^ ((row & 7) << 4))) = f2bf(hn);
        if (gout) gout[(b0 + seg)*100 + j] = hn;
      }
    }
  };

  auto load_x0 = [&](const float* Xb, int t){
    #pragma unroll
    for (int i = 0; i < 4; ++i){
      int gate = TN[i]*16 + colg;
      #pragma unroll
      for (int q = 0; q < 4; ++q){
        int seg = krow*4 + q;
        xp[i][q] = Xb[((size_t)(b0 + seg)*32 + t)*400 + gate];
      }
    }
  };
  auto load_xl1 = [&](const float* Xb, int t){
    #pragma unroll
    for (int i = 0; i < 4; ++i){
      int gate = TN[i]*16 + colg;
      #pragma unroll
      for (int q = 0; q < 4; ++q){
        int seg = krow*4 + q;
        xp[i][q] = Xb[((size_t)t*16 + seg)*400 + gate];
      }
    }
  };

  #pragma unroll 1
  for (int s = 0; s < 2; ++s){
    const float* Xp  = s ? X0r : X0s;
    const float* bi0 = s ? r_bih0 : s_bih0;
    const float* bh0 = s ? r_bhh0 : s_bhh0;
    const float* bi1 = s ? r_bih1 : s_bih1;
    const float* bh1 = s ? r_bhh1 : s_bhh1;
    const int m_whh0 = s ? 3 : 0, m_wih1 = s ? 4 : 1, m_whh1 = s ? 5 : 2;
    float* Xl1 = Xl1ws + ((size_t)blockIdx.x*2 + s)*512*400;

    if (s == 1){
      // h0 carry: copy hbuf slot (32%9)=5 -> slot 0 (phys copy; 80&7==0 so
      // (80+r)&7 == r&7 and the swizzle phase is preserved)
      for (int e = tid; e < 1024; e += 512){
        int r = e >> 6, cc = e & 63;
        ((unsigned int*)hbuf)[r*64 + cc] = ((unsigned int*)hbuf)[(80 + r)*64 + cc];
      }
      __syncthreads();
    }

    float b0r[4], b1r[4];
    #pragma unroll
    for (int i = 0; i < 4; ++i){
      int gate = TN[i]*16 + colg;
      b0r[i] = bi0[gate] + bh0[gate];
      b1r[i] = bi1[gate] + bh1[gate];
    }
    float zr[4] = {0.f, 0.f, 0.f, 0.f};

    // -------- layer 0 (recurrent) + mini-L1a every 8 steps --------
    load_x0(Xp, 0);
    #pragma unroll 1
    for (int c = 0; c < 4; ++c){
      load_frags(m_whh0);
      #pragma unroll 1
      for (int k2 = 0; k2 < 8; ++k2){
        int t = c*8 + k2;
        mm(hbuf, (t % 9)*16);
        act_store(b0r);
        __syncthreads();
        update(cbuf, hbuf, ((t + 1) % 9)*16, nullptr);
        if (t < 31) load_x0(Xp, t + 1);
        __syncthreads();
      }
      // mini-L1a: Xl1[t] = h0out[t] @ wih1^T + bias1 for t in this chunk
      load_frags(m_wih1);
      #pragma unroll 1
      for (int k2 = 0; k2 < 8; ++k2){
        int t = c*8 + k2;
        mm(hbuf, ((t + 1) % 9)*16);
        #pragma unroll
        for (int i = 0; i < 4; ++i){
          if (i == 3 && w != 0) continue;
          int gate = TN[i]*16 + colg;
          #pragma unroll
          for (int q = 0; q < 4; ++q)
            Xl1[((size_t)t*16 + krow*4 + q)*400 + gate] = acc[i][q] + b1r[i];
        }
      }
    }

    // -------- layer 1 (recurrent; x-part from Xl1) --------
    load_frags(m_whh1);
    load_xl1(Xl1, 0);
    __syncthreads();
    #pragma unroll 1
    for (int t = 0; t < 32; ++t){
      mm(h1buf, (t & 1)*16);
      act_store(zr);   // bias already inside Xl1
      __syncthreads();
      update(cbuf + 1664, h1buf, ((t + 1) & 1)*16,
             (t == 31) ? (s ? outR : outS) : nullptr);
      if (t < 31) load_xl1(Xl1, t + 1);
      __syncthreads();
    }
  }
}

// Final head: out = relu([outR|outS] @ fc1^T + b1) @ fc2^T + b2
__global__ __launch_bounds__(256) void head_k(
    const float* __restrict__ outR, const float* __restrict__ outS,
    const float* __restrict__ f1w, const float* __restrict__ f1b,
    const float* __restrict__ f2w, const float* __restrict__ f2b,
    float* __restrict__ out)
{
  __shared__ float xin[200];
  __shared__ float mid[512];
  int b = blockIdx.x, tid = threadIdx.x;
  if (tid < 100) xin[tid] = outR[b*100+tid];
  else if (tid < 200) xin[tid] = outS[b*100+tid-100];
  __syncthreads();
  for (int j = tid; j < 512; j += 256){
    float acc = f1b[j];
    #pragma unroll 4
    for (int k=0;k<200;k++) acc += xin[k]*f1w[j*200+k];
    mid[j] = fmaxf(acc, 0.f);
  }
  __syncthreads();
  if (tid < 130){
    float acc = f2b[tid];
    #pragma unroll 4
    for (int k=0;k<512;k++) acc += mid[k]*f2w[tid*512+k];
    out[b*130+tid] = acc;
  }
}

extern "C" void kernel_launch(void* const* d_in, const int* in_sizes, int n_in,
                              void* d_out, int out_size, void* d_ws, size_t ws_size,
                              hipStream_t stream)
{
  const float* obs  = (const float*)d_in[0];
  const float* data = (const float*)d_in[1];
  const float* c1w = (const float*)d_in[2];  const float* c1b = (const float*)d_in[3];
  const float* c2w = (const float*)d_in[4];  const float* c2b = (const float*)d_in[5];
  const float* c3w = (const float*)d_in[6];  const float* c3b = (const float*)d_in[7];
  const float* l1w = (const float*)d_in[8];  const float* l1b = (const float*)d_in[9];
  const float* l2w = (const float*)d_in[10]; const float* l2b = (const float*)d_in[11];
  const float* s_wih0=(const float*)d_in[12]; const float* s_whh0=(const float*)d_in[13];
  const float* s_bih0=(const float*)d_in[14]; const float* s_bhh0=(const float*)d_in[15];
  const float* s_wih1=(const float*)d_in[16]; const float* s_whh1=(const float*)d_in[17];
  const float* s_bih1=(const float*)d_in[18]; const float* s_bhh1=(const float*)d_in[19];
  const float* r_wih0=(const float*)d_in[20]; const float* r_whh0=(const float*)d_in[21];
  const float* r_bih0=(const float*)d_in[22]; const float* r_bhh0=(const float*)d_in[23];
  const float* r_wih1=(const float*)d_in[24]; const float* r_whh1=(const float*)d_in[25];
  const float* r_bih1=(const float*)d_in[26]; const float* r_bhh1=(const float*)d_in[27];
  const float* f1w=(const float*)d_in[28]; const float* f1b=(const float*)d_in[29];
  const float* f2w=(const float*)d_in[30]; const float* f2b=(const float*)d_in[31];
  float* out = (float*)d_out;
  (void)in_sizes; (void)n_in; (void)out_size;

  // ---- workspace layout (bytes, 256-aligned); total ~ 71 MB ----
  char* p = (char*)d_ws;
  auto alloc = [&](size_t bytes){ void* r = (void*)p; p += (bytes + 255) & ~(size_t)255; return r; };
  unsigned short* data_bf = (unsigned short*)alloc((size_t)2048*1536*2);
  unsigned short* c1w_bf  = (unsigned short*)alloc((size_t)32*192*2);
  unsigned short* c2w_bf  = (unsigned short*)alloc((size_t)64*512*2);
  unsigned short* c3w_bf  = (unsigned short*)alloc((size_t)64*576*2);
  unsigned short* l1w_bf  = (unsigned short*)alloc((size_t)1024*1536*2);
  unsigned short* l2w_bf  = (unsigned short*)alloc((size_t)512*1024*2);
  unsigned short* wihS_bf = (unsigned short*)alloc((size_t)400*1536*2);
  unsigned short* wihR_bf = (unsigned short*)alloc((size_t)400*1536*2);
  unsigned short* conv1o  = (unsigned short*)alloc((size_t)2048*225*32*2);  // NHWC
  unsigned short* conv2o  = (unsigned short*)alloc((size_t)2048*36*64*2);   // NHWC
  unsigned short* feat    = (unsigned short*)alloc((size_t)2048*1536*2);
  unsigned short* lin1o   = (unsigned short*)alloc((size_t)2048*1024*2);
  float* X0s  = (float*)alloc((size_t)1024*400*4);
  float* X0r  = (float*)alloc((size_t)1024*400*4);
  unsigned short* wfrag = (unsigned short*)alloc((size_t)6*51200*2);
  float* Xl1ws = (float*)alloc((size_t)2*2*512*400*4);
  float* outS = (float*)alloc(3200*4);
  float* outR = (float*)alloc(3200*4);
  (void)ws_size;

  // ---- prep ----
  cast_pad_k<<<1024,256,0,stream>>>(data, data_bf, 2048, 1500, 1536);
  cast_pad_k<<<512,256,0,stream>>>(l1w, l1w_bf, 1024, 1500, 1536);
  cast_pad_k<<<512,256,0,stream>>>(l2w, l2w_bf, 512, 1024, 1024);
  cast_pad_k<<<32,256,0,stream>>>(c1w, c1w_bf, 32, 192, 192);
  reorder_w_k<<<128,256,0,stream>>>(c2w, c2w_bf, 64, 32, 16);
  reorder_w_k<<<144,256,0,stream>>>(c3w, c3w_bf, 64, 64, 9);
  permute_wih_k<<<512,256,0,stream>>>(s_wih0, wihS_bf);
  permute_wih_k<<<512,256,0,stream>>>(r_wih0, wihR_bf);
  wfrag_k<<<dim3(50,6),256,0,stream>>>(s_whh0, s_wih1, s_whh1,
                                       r_whh0, r_wih1, r_whh1, wfrag);

  // ---- GEMM chain (bf16 MFMA, fp32 accumulate) ----
  mgemm<128,32,4,1, 1,0,1,0, 3,64,64,8,8,4,15,15><<<dim3(3600,1),256,0,stream>>>(
      obs, c1w_bf, conv1o, c1b, 460800, 32, 192, 0, 32, 0);
  mgemm<128,64,2,2, 2,0,1,0, 32,15,15,4,4,2,6,6><<<dim3(576,1),256,0,stream>>>(
      conv1o, c2w_bf, conv2o, c2b, 73728, 64, 512, 0, 64, 0);
  mgemm<128,64,2,2, 0,0,1,0, 1,1,1,1,1,1,1,1><<<dim3(16,16),256,0,stream>>>(
      data_bf, l1w_bf, lin1o, l1b, 2048, 1024, 1536, 1536, 1024, 0);
  mgemm<128,64,2,2, 2,2,1,0, 64,6,6,3,3,1,4,4><<<dim3(256,1),256,0,stream>>>(
      conv2o, c3w_bf, feat, c3b, 32768, 64, 576, 0, 0, 1536);
  mgemm<128,64,2,2, 0,0,0,0, 1,1,1,1,1,1,1,1><<<dim3(16,8),256,0,stream>>>(
      lin1o, l2w_bf, feat + 1024, l2b, 2048, 512, 1024, 1024, 1536, 0);
  mgemm<128,64,2,2, 0,3,0,1, 1,1,1,1,1,1,1,1><<<dim3(8,7),256,0,stream>>>(
      feat, wihS_bf, X0s, (const float*)nullptr, 1024, 400, 1536, 1536, 400, 0);
  mgemm<128,64,2,2, 0,3,0,1, 1,1,1,1,1,1,1,1><<<dim3(8,7),256,0,stream>>>(
      feat + (size_t)1024*1536, wihR_bf, X0r, (const float*)nullptr, 1024, 400, 1536, 1536, 400, 0);

  // ---- MFMA LSTM + head ----
  lstm_k<<<2,512,0,stream>>>(X0s, X0r, wfrag,
                             s_bih0,s_bhh0,s_bih1,s_bhh1,
                             r_bih0,r_bhh0,r_bih1,r_bhh1,
                             Xl1ws, outS, outR);
  head_k<<<32,256,0,stream>>>(outR, outS, f1w, f1b, f2w, f2b, out);
}

// Round 9
// 346.639 us; speedup vs baseline: 1.5405x; 1.5405x over previous
//
#include <hip/hip_runtime.h>
#include <hip/hip_fp16.h>
#include <math.h>

// ---------------------------------------------------------------------------
// NatureCNN: conv×3 (implicit-im2col bf16 MFMA GEMMs, NHWC intermediates)
// | lin1+relu -> lin2 (bf16 MFMA) -> concat feat -> wih0 pre-act GEMMs (fp32)
// -> 2×(2-layer LSTM, f16-packed fdot2 gate GEMV, 32 blocks, head fused).
// Round 9: r8's raw `v_dot2_f32_bf16` asm produced garbage on gfx950 (only
// delta vs passing r5 besides h-packing, which r7 proved safe). Replace with
// __has_builtin-guarded __builtin_amdgcn_fdot2 on f16 pairs (compiler owns
// encoding); fallback = half2 unpack + FMA (= r5 cost). Also: 9 prep
// launches merged into 1; head fused into lstm_k.
// ---------------------------------------------------------------------------

typedef __attribute__((ext_vector_type(4))) float f32x4;
typedef __attribute__((ext_vector_type(8))) short s16x8;
typedef __attribute__((ext_vector_type(8))) unsigned short u16x8;

__device__ __forceinline__ unsigned short f2bf(float f){
  union { float f; unsigned int u; } v; v.f = f;
  unsigned int r = (v.u + 0x7fffu + ((v.u >> 16) & 1u)) >> 16;
  return (unsigned short)r;
}
__device__ __forceinline__ unsigned short f2h(float f){
  return __half_as_ushort(__float2half(f));
}
__device__ __forceinline__ float sigmoidf_(float x){ return 1.0f/(1.0f+__expf(-x)); }
__device__ __forceinline__ float tanhf_(float x){
  float e = __expf(-2.0f*fabsf(x));
  float t = (1.0f - e)/(1.0f + e);
  return copysignf(t, x);
}

#if __has_builtin(__builtin_amdgcn_fdot2)
typedef _Float16 f16x2 __attribute__((ext_vector_type(2)));
__device__ __forceinline__ float dot2h(unsigned int a, unsigned int b, float c){
  union { unsigned int u; f16x2 h; } ua, ub;
  ua.u = a; ub.u = b;
  return __builtin_amdgcn_fdot2(ua.h, ub.h, c, false);
}
#else
__device__ __forceinline__ float dot2h(unsigned int a, unsigned int b, float c){
  __half2 ha = *(__half2*)&a, hb = *(__half2*)&b;
  float2 fa = __half22float2(ha), fb = __half22float2(hb);
  return c + fa.x*fb.x + fa.y*fb.y;
}
#endif

// ---------------------------------------------------------------------------
// ONE merged prep kernel. blockIdx.y selects the job; grid-stride within job.
//  0: data cast-pad [2048][1500->1536] bf16      1: l1w cast-pad [1024][1500->1536]
//  2: l2w cast [512][1024]                        3: c1w cast [32][192]
//  4: c2w reorder OIHW->O,(tap,ci) 64,32,16       5: c3w reorder 64,64,9
//  6: wihS permute [400][1536] NHWC-k             7: wihR permute
//  8: six recurrent mats -> f16-pair-packed [50][400] u32 each
// ---------------------------------------------------------------------------
__global__ void prep_k(
    const float* __restrict__ data, unsigned short* __restrict__ data_bf,
    const float* __restrict__ l1w,  unsigned short* __restrict__ l1w_bf,
    const float* __restrict__ l2w,  unsigned short* __restrict__ l2w_bf,
    const float* __restrict__ c1w,  unsigned short* __restrict__ c1w_bf,
    const float* __restrict__ c2w,  unsigned short* __restrict__ c2w_bf,
    const float* __restrict__ c3w,  unsigned short* __restrict__ c3w_bf,
    const float* __restrict__ wihS, unsigned short* __restrict__ wihS_bf,
    const float* __restrict__ wihR, unsigned short* __restrict__ wihR_bf,
    const float* __restrict__ m0, const float* __restrict__ m1,
    const float* __restrict__ m2, const float* __restrict__ m3,
    const float* __restrict__ m4, const float* __restrict__ m5,
    unsigned int* __restrict__ wpk)
{
  const int job = blockIdx.y;
  const int stride = gridDim.x * blockDim.x;
  int e0 = blockIdx.x * blockDim.x + threadIdx.x;
  if (job == 0){
    for (int e = e0; e < 2048*1536; e += stride){
      int r = e >> 9; r = e / 1536; int k = e - r*1536;
      data_bf[e] = (k < 1500) ? f2bf(data[(size_t)r*1500 + k]) : (unsigned short)0;
    }
  } else if (job == 1){
    for (int e = e0; e < 1024*1536; e += stride){
      int r = e / 1536, k = e - r*1536;
      l1w_bf[e] = (k < 1500) ? f2bf(l1w[(size_t)r*1500 + k]) : (unsigned short)0;
    }
  } else if (job == 2){
    for (int e = e0; e < 512*1024; e += stride) l2w_bf[e] = f2bf(l2w[e]);
  } else if (job == 3){
    for (int e = e0; e < 32*192; e += stride) c1w_bf[e] = f2bf(c1w[e]);
  } else if (job == 4){
    for (int e = e0; e < 64*512; e += stride){
      int oc = e >> 9, r = e & 511;
      int tap = r >> 5, ic = r & 31;
      c2w_bf[e] = f2bf(c2w[(size_t)oc*512 + ic*16 + tap]);
    }
  } else if (job == 5){
    for (int e = e0; e < 64*576; e += stride){
      int oc = e / 576, r = e - oc*576;
      int tap = r >> 6, ic = r & 63;
      c3w_bf[e] = f2bf(c3w[(size_t)oc*576 + ic*9 + tap]);
    }
  } else if (job == 6 || job == 7){
    const float* src = (job == 6) ? wihS : wihR;
    unsigned short* dst = (job == 6) ? wihS_bf : wihR_bf;
    for (int e = e0; e < 400*1536; e += stride){
      int g = e / 1536, k = e - g*1536;
      int ksrc = (k < 1024) ? ((k & 63)*16 + (k >> 6)) : k;
      dst[e] = f2bf(src[(size_t)g*1536 + ksrc]);
    }
  } else {
    const float* srcs[6] = {m0,m1,m2,m3,m4,m5};
    for (int e = e0; e < 6*20000; e += stride){
      int mat = e / 20000, r = e - mat*20000;
      int kk = r / 400, g = r - kk*400;
      const float* src = srcs[mat];
      unsigned int lo = f2h(src[g*100 + 2*kk]);
      unsigned int hi = f2h(src[g*100 + 2*kk + 1]);
      wpk[e] = lo | (hi << 16);
    }
  }
}

// ---------------------------------------------------------------------------
// bf16 MFMA GEMM (unchanged, passing since round 2)
// ---------------------------------------------------------------------------
template<int BM,int BN,int WAVES_M,int WAVES_N,int AMODE,int CMODE,int RELU,int NGUARD,
         int CIN,int HI,int WI,int KH,int KW,int ST,int HO,int WO>
__global__ __launch_bounds__(256) void mgemm(
    const void* __restrict__ Av, const unsigned short* __restrict__ B,
    void* __restrict__ Cv, const float* __restrict__ bias,
    int M, int N, int K, int lda, int ldc, int cstride)
{
  constexpr int BK = 64;
  constexpr int WROWS = BM / WAVES_M;
  constexpr int WCOLS = BN / WAVES_N;
  constexpr int MF = WROWS / 16;
  constexpr int NF = WCOLS / 16;
  constexpr int HOWO = HO*WO;
  __shared__ unsigned short As[BM*BK];
  __shared__ unsigned short Bs[BN*BK];
  const int tid = threadIdx.x;
  const int bm = blockIdx.x * BM;
  const int bn = blockIdx.y * BN;
  const int lane = tid & 63, w = tid >> 6;
  const int wm = w / WAVES_N, wn = w % WAVES_N;
  const int m0 = wm * WROWS, n0 = wn * WCOLS;

  f32x4 acc[MF][NF] = {};

  const int ar = tid >> 1;
  const int as0 = 4 * (tid & 1);
  const int row_g = bm + ar;
  int a_n = 0, a_oy = 0, a_ox = 0;
  if (AMODE != 0){ a_n = row_g / HOWO; int p = row_g - a_n*HOWO; a_oy = p / WO; a_ox = p - a_oy*WO; }

  for (int kt = 0; kt < K; kt += BK){
    #pragma unroll
    for (int si = 0; si < 4; ++si){
      int s = as0 + si;
      int k0 = kt + s*8;
      u16x8 val;
      if constexpr (AMODE == 0){
        val = *(const u16x8*)((const unsigned short*)Av + (size_t)row_g*lda + k0);
      } else if constexpr (AMODE == 1){
        int ic = k0 >> 6, r = k0 & 63, ky = r >> 3;
        const float* src = (const float*)Av +
            (((size_t)(a_n*CIN + ic)*HI + a_oy*ST + ky)*WI + a_ox*ST);
        f32x4 f0 = *(const f32x4*)src;
        f32x4 f1 = *(const f32x4*)(src + 4);
        val[0]=f2bf(f0[0]); val[1]=f2bf(f0[1]); val[2]=f2bf(f0[2]); val[3]=f2bf(f0[3]);
        val[4]=f2bf(f1[0]); val[5]=f2bf(f1[1]); val[6]=f2bf(f1[2]); val[7]=f2bf(f1[3]);
      } else {
        int tap = k0 / CIN, ic0 = k0 - tap*CIN;
        int ky = tap / KW, kx = tap - ky*KW;
        const unsigned short* src = (const unsigned short*)Av +
            (((size_t)(a_n*HI + a_oy*ST + ky)*WI + a_ox*ST + kx)*CIN + ic0);
        val = *(const u16x8*)src;
      }
      int phys = s ^ ((ar >> 1) & 7);
      *(u16x8*)&As[ar*BK + phys*8] = val;
    }
    if constexpr (BN == 64){
      int br = tid >> 2, bs0 = 2*(tid & 3);
      #pragma unroll
      for (int si = 0; si < 2; ++si){
        int s = bs0 + si, k0 = kt + s*8;
        int n_g = bn + br;
        u16x8 val = {};
        if (!NGUARD || n_g < N) val = *(const u16x8*)(B + (size_t)n_g*K + k0);
        int phys = s ^ ((br >> 1) & 7);
        *(u16x8*)&Bs[br*BK + phys*8] = val;
      }
    } else {
      int br = tid >> 3, s = tid & 7, k0 = kt + s*8;
      int n_g = bn + br;
      u16x8 val = {};
      if (!NGUARD || n_g < N) val = *(const u16x8*)(B + (size_t)n_g*K + k0);
      int phys = s ^ ((br >> 1) & 7);
      *(u16x8*)&Bs[br*BK + phys*8] = val;
    }
    __syncthreads();
    #pragma unroll
    for (int ks = 0; ks < 2; ++ks){
      s16x8 a[MF], b[NF];
      #pragma unroll
      for (int i = 0; i < MF; ++i){
        int row = m0 + i*16 + (lane & 15);
        int phys = (ks*4 + (lane >> 4)) ^ ((row >> 1) & 7);
        a[i] = *(const s16x8*)&As[row*BK + phys*8];
      }
      #pragma unroll
      for (int j = 0; j < NF; ++j){
        int row = n0 + j*16 + (lane & 15);
        int phys = (ks*4 + (lane >> 4)) ^ ((row >> 1) & 7);
        b[j] = *(const s16x8*)&Bs[row*BK + phys*8];
      }
      #pragma unroll
      for (int i = 0; i < MF; ++i)
        #pragma unroll
        for (int j = 0; j < NF; ++j)
          acc[i][j] = __builtin_amdgcn_mfma_f32_16x16x32_bf16(a[i], b[j], acc[i][j], 0, 0, 0);
    }
    __syncthreads();
  }

  if constexpr (CMODE == 3){
    float* Cf = (float*)Cv;
    #pragma unroll
    for (int i = 0; i < MF; ++i)
      #pragma unroll
      for (int j = 0; j < NF; ++j){
        int col = bn + n0 + j*16 + (lane & 15);
        float bv = (bias && (!NGUARD || col < N)) ? bias[col] : 0.f;
        #pragma unroll
        for (int q = 0; q < 4; ++q){
          int row = bm + m0 + i*16 + (lane >> 4)*4 + q;
          float v = acc[i][j][q] + bv;
          if (RELU) v = fmaxf(v, 0.f);
          if (!NGUARD || col < N) Cf[(size_t)row*ldc + col] = v;
        }
      }
  } else {
    unsigned short* tile = As;
    #pragma unroll
    for (int i = 0; i < MF; ++i)
      #pragma unroll
      for (int j = 0; j < NF; ++j){
        int col = n0 + j*16 + (lane & 15);
        float bv = bias ? bias[bn + col] : 0.f;
        #pragma unroll
        for (int q = 0; q < 4; ++q){
          int row = m0 + i*16 + (lane >> 4)*4 + q;
          float v = acc[i][j][q] + bv;
          if (RELU) v = fmaxf(v, 0.f);
          tile[row*BN + col] = f2bf(v);
        }
      }
    __syncthreads();
    unsigned short* Cu = (unsigned short*)Cv;
    constexpr int CHUNKS = (BM*BN)/(256*8);
    #pragma unroll
    for (int c = 0; c < CHUNKS; ++c){
      int flat = tid*8 + c*2048;
      int row = flat / BN, col = flat - (flat/BN)*BN;
      u16x8 v = *(const u16x8*)&tile[flat];
      int rg = bm + row;
      size_t addr;
      if constexpr (CMODE == 0) addr = (size_t)rg*ldc + bn + col;
      else { int n = rg >> 4, p = rg & 15; addr = (size_t)n*cstride + p*64 + col; }
      *(u16x8*)&Cu[addr] = v;
    }
  }
}

// ---------------------------------------------------------------------------
// LSTM (r5 structure): one block per segment; both stacks. 832 threads;
// thread pair (2g, 2g+1) owns gate g with a 50/50 k-split. Weights AND h as
// f16 pairs packed in u32 (weights in 25 VGPRs; h in LDS). Inner iter =
// 1 ds_read_b32 + 1 fdot2 (or unpack+FMA fallback). Gate threads apply
// sigmoid/tanh (400-way parallel); tid<100 combiner does the c/h update.
// Head (fc1+relu+fc2) fused at the end using the block's own final h rows.
// ---------------------------------------------------------------------------
__global__ __launch_bounds__(832,4) void lstm_k(
    const float* __restrict__ X0s, const float* __restrict__ X0r,
    const unsigned int* __restrict__ wpk,  // 6 x [50][400] u32 packed f16 pairs
    const float* __restrict__ s_bih0, const float* __restrict__ s_bhh0,
    const float* __restrict__ s_bih1, const float* __restrict__ s_bhh1,
    const float* __restrict__ r_bih0, const float* __restrict__ r_bhh0,
    const float* __restrict__ r_bih1, const float* __restrict__ r_bhh1,
    const float* __restrict__ f1w, const float* __restrict__ f1b,
    const float* __restrict__ f2w, const float* __restrict__ f2b,
    float* __restrict__ out)
{
  __shared__ alignas(16) unsigned int h0p[52];     // 50 f16 pairs (+pad)
  __shared__ alignas(16) unsigned int h1p[52];
  __shared__ alignas(16) float c0[104];
  __shared__ alignas(16) float c1[104];
  __shared__ float gates[400];                     // ACTIVATED gate values
  __shared__ alignas(16) unsigned int hbufp[1664]; // 32 steps x 52 u32
  __shared__ alignas(16) float Xl1[12800];         // layer-1 x-part, 32 x 400
  __shared__ float xin[208];                       // head input [outR|outS]
  __shared__ float mid[512];                       // head hidden

  const int b = blockIdx.x, tid = threadIdx.x;
  const int g = tid >> 1, half = tid & 1;
  const bool act = (tid < 800);                // g < 400
  const int kb = half * 25;                    // packed-pair base (k = 2*kb)
  const bool isG = (g >= 200) & (g < 300);     // tanh gate vs sigmoid gates

  if (tid < 52){ h0p[tid] = 0u; h1p[tid] = 0u; }
  if (tid < 104){ c0[tid] = 0.f; c1[tid] = 0.f; }
  __syncthreads();

  #pragma unroll 1
  for (int s = 0; s < 2; ++s){
    const float* Xp = (s ? X0r : X0s) + (size_t)b*32*400;
    const unsigned int* w0P  = wpk + (size_t)(s ? 3 : 0)*20000;
    const unsigned int* w1xP = wpk + (size_t)(s ? 4 : 1)*20000;
    const unsigned int* w1hP = wpk + (size_t)(s ? 5 : 2)*20000;
    const float* bi0 = s ? r_bih0 : s_bih0;
    const float* bh0 = s ? r_bhh0 : s_bhh0;
    const float* bi1 = s ? r_bih1 : s_bih1;
    const float* bh1 = s ? r_bhh1 : s_bhh1;

    // ------------- layer 0 (recurrent) -------------
    {
      unsigned int wrp[25];
      float bsum = 0.f, xcur = 0.f;
      if (act){
        #pragma unroll
        for (int j = 0; j < 25; ++j) wrp[j] = w0P[(kb + j)*400 + g];
        if (!half){ bsum = bi0[g] + bh0[g]; xcur = Xp[g]; }
      }
      #pragma unroll 1
      for (int t = 0; t < 32; ++t){
        float xnext = 0.f;
        if (act && !half && t < 31) xnext = Xp[(t+1)*400 + g];
        if (act){
          float p0 = 0.f, p1 = 0.f;
          #pragma unroll
          for (int j = 0; j < 25; j += 2){
            p0 = dot2h(wrp[j], h0p[kb + j], p0);
            if (j + 1 < 25) p1 = dot2h(wrp[j+1], h0p[kb + j + 1], p1);
          }
          float part = p0 + p1;
          float full = part + __shfl_xor(part, 1);
          if (!half){
            float pre = xcur + bsum + full;
            gates[g] = isG ? tanhf_(pre) : sigmoidf_(pre);
          }
        }
        __syncthreads();
        if (tid < 100){
          float cn = gates[100+tid]*c0[tid] + gates[tid]*gates[200+tid];
          c0[tid] = cn;
          float hn = gates[300+tid]*tanhf_(cn);
          unsigned short hb = f2h(hn);
          ((unsigned short*)h0p)[tid] = hb;
          ((unsigned short*)hbufp)[t*104 + tid] = hb;
        }
        __syncthreads();
        xcur = xnext;
      }
    }
    // ------------- layer 1a: x-part pre-acts (no recurrence) -------------
    {
      unsigned int wxp[25];
      float bsum = 0.f;
      if (act){
        #pragma unroll
        for (int j = 0; j < 25; ++j) wxp[j] = w1xP[(kb + j)*400 + g];
        if (!half) bsum = bi1[g] + bh1[g];
        #pragma unroll 1
        for (int t = 0; t < 32; ++t){
          const unsigned int* x2 = hbufp + t*52;
          float p0 = 0.f, p1 = 0.f;
          #pragma unroll
          for (int j = 0; j < 25; j += 2){
            p0 = dot2h(wxp[j], x2[kb + j], p0);
            if (j + 1 < 25) p1 = dot2h(wxp[j+1], x2[kb + j + 1], p1);
          }
          float part = p0 + p1;
          float full = part + __shfl_xor(part, 1);
          if (!half) Xl1[t*400+g] = bsum + full;
        }
      }
      __syncthreads();
    }
    // ------------- layer 1b: recurrent -------------
    {
      unsigned int whp[25];
      if (act){
        #pragma unroll
        for (int j = 0; j < 25; ++j) whp[j] = w1hP[(kb + j)*400 + g];
      }
      #pragma unroll 1
      for (int t = 0; t < 32; ++t){
        if (act){
          float p0 = 0.f, p1 = 0.f;
          #pragma unroll
          for (int j = 0; j < 25; j += 2){
            p0 = dot2h(whp[j], h1p[kb + j], p0);
            if (j + 1 < 25) p1 = dot2h(whp[j+1], h1p[kb + j + 1], p1);
          }
          float part = p0 + p1;
          float full = part + __shfl_xor(part, 1);
          if (!half){
            float pre = Xl1[t*400+g] + full;
            gates[g] = isG ? tanhf_(pre) : sigmoidf_(pre);
          }
        }
        __syncthreads();
        if (tid < 100){
          float cn = gates[100+tid]*c1[tid] + gates[tid]*gates[200+tid];
          c1[tid] = cn;
          float hn = gates[300+tid]*tanhf_(cn);
          ((unsigned short*)h1p)[tid] = f2h(hn);
          if (t == 31){
            if (s) xin[tid] = hn;        // outR -> head cols [0,100)
            else   xin[100 + tid] = hn;  // outS -> head cols [100,200)
          }
        }
        __syncthreads();
      }
    }
  }

  // ------------- fused head: out[b] = relu(xin@f1w^T+b1)@f2w^T+b2 -------------
  if (tid < 512){
    float acc = f1b[tid];
    const float* wrow = f1w + (size_t)tid*200;
    #pragma unroll 4
    for (int k = 0; k < 200; ++k) acc += xin[k]*wrow[k];
    mid[tid] = fmaxf(acc, 0.f);
  }
  __syncthreads();
  if (tid < 130){
    float acc = f2b[tid];
    const float* wrow = f2w + (size_t)tid*512;
    #pragma unroll 4
    for (int k = 0; k < 512; ++k) acc += mid[k]*wrow[k];
    out[b*130 + tid] = acc;
  }
}

extern "C" void kernel_launch(void* const* d_in, const int* in_sizes, int n_in,
                              void* d_out, int out_size, void* d_ws, size_t ws_size,
                              hipStream_t stream)
{
  const float* obs  = (const float*)d_in[0];
  const float* data = (const float*)d_in[1];
  const float* c1w = (const float*)d_in[2];  const float* c1b = (const float*)d_in[3];
  const float* c2w = (const float*)d_in[4];  const float* c2b = (const float*)d_in[5];
  const float* c3w = (const float*)d_in[6];  const float* c3b = (const float*)d_in[7];
  const float* l1w = (const float*)d_in[8];  const float* l1b = (const float*)d_in[9];
  const float* l2w = (const float*)d_in[10]; const float* l2b = (const float*)d_in[11];
  const float* s_wih0=(const float*)d_in[12]; const float* s_whh0=(const float*)d_in[13];
  const float* s_bih0=(const float*)d_in[14]; const float* s_bhh0=(const float*)d_in[15];
  const float* s_wih1=(const float*)d_in[16]; const float* s_whh1=(const float*)d_in[17];
  const float* s_bih1=(const float*)d_in[18]; const float* s_bhh1=(const float*)d_in[19];
  const float* r_wih0=(const float*)d_in[20]; const float* r_whh0=(const float*)d_in[21];
  const float* r_bih0=(const float*)d_in[22]; const float* r_bhh0=(const float*)d_in[23];
  const float* r_wih1=(const float*)d_in[24]; const float* r_whh1=(const float*)d_in[25];
  const float* r_bih1=(const float*)d_in[26]; const float* r_bhh1=(const float*)d_in[27];
  const float* f1w=(const float*)d_in[28]; const float* f1b=(const float*)d_in[29];
  const float* f2w=(const float*)d_in[30]; const float* f2b=(const float*)d_in[31];
  float* out = (float*)d_out;
  (void)in_sizes; (void)n_in; (void)out_size;

  // ---- workspace layout (bytes, 256-aligned); total ~ 67 MB ----
  char* p = (char*)d_ws;
  auto alloc = [&](size_t bytes){ void* r = (void*)p; p += (bytes + 255) & ~(size_t)255; return r; };
  unsigned short* data_bf = (unsigned short*)alloc((size_t)2048*1536*2);
  unsigned short* c1w_bf  = (unsigned short*)alloc((size_t)32*192*2);
  unsigned short* c2w_bf  = (unsigned short*)alloc((size_t)64*512*2);
  unsigned short* c3w_bf  = (unsigned short*)alloc((size_t)64*576*2);
  unsigned short* l1w_bf  = (unsigned short*)alloc((size_t)1024*1536*2);
  unsigned short* l2w_bf  = (unsigned short*)alloc((size_t)512*1024*2);
  unsigned short* wihS_bf = (unsigned short*)alloc((size_t)400*1536*2);
  unsigned short* wihR_bf = (unsigned short*)alloc((size_t)400*1536*2);
  unsigned short* conv1o  = (unsigned short*)alloc((size_t)2048*225*32*2);  // NHWC
  unsigned short* conv2o  = (unsigned short*)alloc((size_t)2048*36*64*2);   // NHWC
  unsigned short* feat    = (unsigned short*)alloc((size_t)2048*1536*2);
  unsigned short* lin1o   = (unsigned short*)alloc((size_t)2048*1024*2);
  float* X0s  = (float*)alloc((size_t)1024*400*4);
  float* X0r  = (float*)alloc((size_t)1024*400*4);
  unsigned int* wpk = (unsigned int*)alloc((size_t)6*20000*4);
  (void)ws_size;

  // ---- merged prep (1 launch) ----
  prep_k<<<dim3(512,9),256,0,stream>>>(
      data, data_bf, l1w, l1w_bf, l2w, l2w_bf, c1w, c1w_bf,
      c2w, c2w_bf, c3w, c3w_bf, s_wih0, wihS_bf, r_wih0, wihR_bf,
      s_whh0, s_wih1, s_whh1, r_whh0, r_wih1, r_whh1, wpk);

  // ---- GEMM chain (bf16 MFMA, fp32 accumulate) ----
  // conv1: M=460800 N=32 K=192, obs fp32 NCHW gather -> NHWC bf16
  mgemm<128,32,4,1, 1,0,1,0, 3,64,64,8,8,4,15,15><<<dim3(3600,1),256,0,stream>>>(
      obs, c1w_bf, conv1o, c1b, 460800, 32, 192, 0, 32, 0);
  // conv2: M=73728 N=64 K=512, NHWC gather -> NHWC bf16
  mgemm<128,64,2,2, 2,0,1,0, 32,15,15,4,4,2,6,6><<<dim3(576,1),256,0,stream>>>(
      conv1o, c2w_bf, conv2o, c2b, 73728, 64, 512, 0, 64, 0);
  // lin1: M=2048 N=1024 K=1536(padded) -> bf16
  mgemm<128,64,2,2, 0,0,1,0, 1,1,1,1,1,1,1,1><<<dim3(16,16),256,0,stream>>>(
      data_bf, l1w_bf, lin1o, l1b, 2048, 1024, 1536, 1536, 1024, 0);
  // conv3: M=32768 N=64 K=576 -> feat cols [0,1024) in NHWC-flat order
  mgemm<128,64,2,2, 2,2,1,0, 64,6,6,3,3,1,4,4><<<dim3(256,1),256,0,stream>>>(
      conv2o, c3w_bf, feat, c3b, 32768, 64, 576, 0, 0, 1536);
  // lin2: M=2048 N=512 K=1024 -> feat cols [1024,1536)
  mgemm<128,64,2,2, 0,0,0,0, 1,1,1,1,1,1,1,1><<<dim3(16,8),256,0,stream>>>(
      lin1o, l2w_bf, feat + 1024, l2b, 2048, 512, 1024, 1024, 1536, 0);
  // LSTM layer-0 input pre-acts (fp32 out, no bias)
  mgemm<128,64,2,2, 0,3,0,1, 1,1,1,1,1,1,1,1><<<dim3(8,7),256,0,stream>>>(
      feat, wihS_bf, X0s, (const float*)nullptr, 1024, 400, 1536, 1536, 400, 0);
  mgemm<128,64,2,2, 0,3,0,1, 1,1,1,1,1,1,1,1><<<dim3(8,7),256,0,stream>>>(
      feat + (size_t)1024*1536, wihR_bf, X0r, (const float*)nullptr, 1024, 400, 1536, 1536, 400, 0);

  // ---- sequential LSTM + fused head ----
  lstm_k<<<32,832,0,stream>>>(X0s, X0r, wpk,
                              s_bih0,s_bhh0,s_bih1,s_bhh1,
                              r_bih0,r_bhh0,r_bih1,r_bhh1,
                              f1w, f1b, f2w, f2b, out);
}